// Round 1
// 1030.654 us; speedup vs baseline: 1.1171x; 1.1171x over previous
//
#include <hip/hip_runtime.h>

#define EXPERTS 8
#define ODIM 4096
#define IDIM 1024
#define BATCH 16
#define SEQ 2048

#define BM 128
#define BN 128
#define BK 32
#define LDSS 40   // fallback-kernel LDS stride

typedef __attribute__((ext_vector_type(8))) short bf16x8;
typedef __attribute__((ext_vector_type(4))) float f32x4;

__device__ __forceinline__ unsigned short to_bf16(float f) {
    union { float f; unsigned u; } v; v.f = f;
    // round-to-nearest-even
    return (unsigned short)((v.u + 0x7FFFu + ((v.u >> 16) & 1u)) >> 16);
}

__device__ __forceinline__ void gload_lds16(const unsigned short* g, unsigned short* l) {
    // async global->LDS, 16B/lane; LDS dest = wave-uniform base + lane*16 [m104]
    __builtin_amdgcn_global_load_lds(
        (const __attribute__((address_space(1))) void*)g,
        (__attribute__((address_space(3))) void*)l,
        16, 0, 0);
}

// ---------------- pass 1: fp32 -> bf16 for x and all expert weights ----------------
__global__ __launch_bounds__(256)
void convert_bf16_kernel(const float* __restrict__ x, const float* __restrict__ w,
                         unsigned short* __restrict__ xb, unsigned short* __restrict__ wb) {
    const size_t NX = (size_t)BATCH * SEQ * IDIM;
    const size_t NT = NX + (size_t)EXPERTS * ODIM * IDIM;
    const size_t stride = (size_t)gridDim.x * blockDim.x * 8;
    for (size_t i = ((size_t)blockIdx.x * blockDim.x + threadIdx.x) * 8; i < NT; i += stride) {
        const float* src; unsigned short* dst; size_t off;
        if (i < NX) { src = x; dst = xb; off = i; }
        else        { src = w; dst = wb; off = i - NX; }
        const f32x4 v0 = *(const f32x4*)(src + off);
        const f32x4 v1 = *(const f32x4*)(src + off + 4);
        union { unsigned short s[8]; bf16x8 v; } o;
        o.s[0] = to_bf16(v0.x); o.s[1] = to_bf16(v0.y);
        o.s[2] = to_bf16(v0.z); o.s[3] = to_bf16(v0.w);
        o.s[4] = to_bf16(v1.x); o.s[5] = to_bf16(v1.y);
        o.s[6] = to_bf16(v1.z); o.s[7] = to_bf16(v1.w);
        *(bf16x8*)(dst + off) = o.v;
    }
}

// ---------------- pass 2: m97-structure bf16 GEMM (128x128 tile, BK=32, gload_lds) ----------------
__global__ __launch_bounds__(256)
void moe_gemm_bf16(const unsigned short* __restrict__ xb,
                   const unsigned short* __restrict__ wb,
                   const float* __restrict__ probs,
                   const float* __restrict__ bias,
                   float* __restrict__ out) {
    __shared__ unsigned short As[BM * BK];   // linear: required by global_load_lds
    __shared__ unsigned short Bs[BN * BK];
    __shared__ int s_e;

    const int tn  = blockIdx.x;   // n tile
    const int tm  = blockIdx.y;   // m tile
    const int b   = blockIdx.z;   // batch
    const int tid = threadIdx.x;

    if (tid == 0) {
        float best = probs[b * EXPERTS];
        int bi = 0;
        #pragma unroll
        for (int e2 = 1; e2 < EXPERTS; ++e2) {
            float p = probs[b * EXPERTS + e2];
            if (p > best) { best = p; bi = e2; }
        }
        s_e = bi;
    }
    __syncthreads();
    const int e = s_e;

    const int m0 = tm * BM;
    const int n0 = tn * BN;
    const int lane = tid & 63;
    const int wave = tid >> 6;

    // staging map: lane of wave wv covers LDS bytes [p*4096 + wv*1024 + lane*16)
    // -> tile row p*64 + wv*16 + lane/4, k-col (lane%4)*8  (row stride 64B at BK=32)
    const int srow = wave * 16 + (lane >> 2);
    const int scol = (lane & 3) * 8;
    const unsigned short* ag = xb + ((size_t)b * SEQ + m0 + srow) * IDIM + scol;
    const unsigned short* bg = wb + ((size_t)e * ODIM + n0 + srow) * IDIM + scol;
    unsigned short* lA = As + wave * 512;   // wave-uniform base (elements); HW adds lane*16B
    unsigned short* lB = Bs + wave * 512;

    const int wm = (wave & 1) * 64;   // wave's 64x64 quadrant
    const int wn = (wave >> 1) * 64;
    const int frow = lane & 15;       // fragment row (A: m, B: n)
    const int fk   = (lane >> 4) * 8; // fragment k offset

    f32x4 acc[4][4];
    #pragma unroll
    for (int i = 0; i < 4; ++i)
        #pragma unroll
        for (int j = 0; j < 4; ++j)
            acc[i][j] = (f32x4){0.f, 0.f, 0.f, 0.f};

    for (int k0 = 0; k0 < IDIM; k0 += BK) {
        // ---- async stage A,B tiles (4 x global_load_lds_dwordx4 per thread) ----
        gload_lds16(ag + k0,                      lA);
        gload_lds16(ag + k0 + (size_t)64 * IDIM,  lA + 2048);
        gload_lds16(bg + k0,                      lB);
        gload_lds16(bg + k0 + (size_t)64 * IDIM,  lB + 2048);
        __syncthreads();   // compiler emits vmcnt(0) drain before barrier

        // ---- LDS -> fragments -> MFMA ----
        bf16x8 a_frag[4], b_frag[4];
        #pragma unroll
        for (int i = 0; i < 4; ++i)
            a_frag[i] = *(const bf16x8*)&As[(wm + i * 16 + frow) * BK + fk];
        #pragma unroll
        for (int j = 0; j < 4; ++j)
            b_frag[j] = *(const bf16x8*)&Bs[(wn + j * 16 + frow) * BK + fk];

        #pragma unroll
        for (int i = 0; i < 4; ++i)
            #pragma unroll
            for (int j = 0; j < 4; ++j)
                acc[i][j] = __builtin_amdgcn_mfma_f32_16x16x32_bf16(
                    a_frag[i], b_frag[j], acc[i][j], 0, 0, 0);
        __syncthreads();
    }

    // ---- epilogue: + bias, store fp32 ----
    // C/D layout: col = lane&15, row = (lane>>4)*4 + reg   [m89-verified]
    const float* bias_e = bias + (size_t)e * ODIM;
    const int rbase = (lane >> 4) * 4;
    #pragma unroll
    for (int j = 0; j < 4; ++j) {
        const int n = n0 + wn + j * 16 + frow;
        const float bv = bias_e[n];
        #pragma unroll
        for (int i = 0; i < 4; ++i) {
            const int mb = m0 + wm + i * 16 + rbase;
            float* op = out + ((size_t)b * SEQ + mb) * ODIM + n;
            #pragma unroll
            for (int r = 0; r < 4; ++r)
                op[(size_t)r * ODIM] = acc[i][j][r] + bv;
        }
    }
}

// ---------------- fallback (previous verified kernel) if workspace too small ----------------
__global__ __launch_bounds__(256)
void moe_gemm_fallback(const float* __restrict__ x,
                       const float* __restrict__ probs,
                       const float* __restrict__ w,
                       const float* __restrict__ bias,
                       float* __restrict__ out) {
    __shared__ unsigned short As[BM * LDSS];
    __shared__ unsigned short Bs[BN * LDSS];
    __shared__ int s_e;

    const int tn  = blockIdx.x;
    const int tm  = blockIdx.y;
    const int b   = blockIdx.z;
    const int tid = threadIdx.x;

    if (tid == 0) {
        float best = probs[b * EXPERTS];
        int bi = 0;
        #pragma unroll
        for (int e2 = 1; e2 < EXPERTS; ++e2) {
            float p = probs[b * EXPERTS + e2];
            if (p > best) { best = p; bi = e2; }
        }
        s_e = bi;
    }
    __syncthreads();
    const int e = s_e;

    const int m0 = tm * BM;
    const int n0 = tn * BN;
    const int srow = tid >> 3;
    const int scol = (tid & 7) * 4;

    const float* ag = x + ((size_t)b * SEQ + m0 + srow) * IDIM + scol;
    const float* bg = w + ((size_t)e * ODIM + n0 + srow) * IDIM + scol;

    const int lane = tid & 63;
    const int wave = tid >> 6;
    const int wm = (wave & 1) * 64;
    const int wn = (wave >> 1) * 64;
    const int frow = lane & 15;
    const int fk   = (lane >> 4) * 8;

    f32x4 acc[4][4];
    #pragma unroll
    for (int i = 0; i < 4; ++i)
        #pragma unroll
        for (int j = 0; j < 4; ++j)
            acc[i][j] = (f32x4){0.f, 0.f, 0.f, 0.f};

    for (int k0 = 0; k0 < IDIM; k0 += BK) {
        #pragma unroll
        for (int p = 0; p < 4; ++p) {
            const f32x4 av = *(const f32x4*)(ag + (size_t)p * 32 * IDIM);
            const f32x4 bv = *(const f32x4*)(bg + (size_t)p * 32 * IDIM);
            const int r = srow + p * 32;
            union { unsigned short s[4]; unsigned long long u; } pa, pb;
            pa.s[0] = to_bf16(av.x); pa.s[1] = to_bf16(av.y);
            pa.s[2] = to_bf16(av.z); pa.s[3] = to_bf16(av.w);
            pb.s[0] = to_bf16(bv.x); pb.s[1] = to_bf16(bv.y);
            pb.s[2] = to_bf16(bv.z); pb.s[3] = to_bf16(bv.w);
            *(unsigned long long*)&As[r * LDSS + scol] = pa.u;
            *(unsigned long long*)&Bs[r * LDSS + scol] = pb.u;
        }
        __syncthreads();

        bf16x8 a_frag[4], b_frag[4];
        #pragma unroll
        for (int i = 0; i < 4; ++i)
            a_frag[i] = *(const bf16x8*)&As[(wm + i * 16 + frow) * LDSS + fk];
        #pragma unroll
        for (int j = 0; j < 4; ++j)
            b_frag[j] = *(const bf16x8*)&Bs[(wn + j * 16 + frow) * LDSS + fk];

        #pragma unroll
        for (int i = 0; i < 4; ++i)
            #pragma unroll
            for (int j = 0; j < 4; ++j)
                acc[i][j] = __builtin_amdgcn_mfma_f32_16x16x32_bf16(
                    a_frag[i], b_frag[j], acc[i][j], 0, 0, 0);
        __syncthreads();

        ag += BK;
        bg += BK;
    }

    const float* bias_e = bias + (size_t)e * ODIM;
    const int rbase = (lane >> 4) * 4;
    #pragma unroll
    for (int j = 0; j < 4; ++j) {
        const int n = n0 + wn + j * 16 + frow;
        const float bv = bias_e[n];
        #pragma unroll
        for (int i = 0; i < 4; ++i) {
            const int mb = m0 + wm + i * 16 + rbase;
            float* op = out + ((size_t)b * SEQ + mb) * ODIM + n;
            #pragma unroll
            for (int r = 0; r < 4; ++r)
                op[(size_t)r * ODIM] = acc[i][j][r] + bv;
        }
    }
}

__global__ void moe_idx_kernel(const float* __restrict__ probs,
                               float* __restrict__ out_idx) {
    const int b = threadIdx.x;
    if (b < BATCH) {
        float best = probs[b * EXPERTS];
        int bi = 0;
        #pragma unroll
        for (int e2 = 1; e2 < EXPERTS; ++e2) {
            float p = probs[b * EXPERTS + e2];
            if (p > best) { best = p; bi = e2; }
        }
        out_idx[b] = (float)bi;
    }
}

extern "C" void kernel_launch(void* const* d_in, const int* in_sizes, int n_in,
                              void* d_out, int out_size, void* d_ws, size_t ws_size,
                              hipStream_t stream) {
    const float* x     = (const float*)d_in[0];
    const float* probs = (const float*)d_in[1];
    const float* w     = (const float*)d_in[2];
    const float* bias  = (const float*)d_in[3];
    float* out = (float*)d_out;

    const size_t nxb = (size_t)BATCH * SEQ * IDIM;      // bf16 elements for x
    const size_t nwb = (size_t)EXPERTS * ODIM * IDIM;   // bf16 elements for w
    const size_t need = (nxb + nwb) * sizeof(unsigned short);  // 128 MiB

    dim3 grid(ODIM / BN, SEQ / BM, BATCH);   // 32 x 16 x 16 = 8192 blocks

    if (ws_size >= need) {
        unsigned short* xbuf = (unsigned short*)d_ws;
        unsigned short* wbuf = xbuf + nxb;
        convert_bf16_kernel<<<2048, 256, 0, stream>>>(x, w, xbuf, wbuf);
        moe_gemm_bf16<<<grid, 256, 0, stream>>>(xbuf, wbuf, probs, bias, out);
    } else {
        moe_gemm_fallback<<<grid, 256, 0, stream>>>(x, probs, w, bias, out);
    }
    moe_idx_kernel<<<1, 64, 0, stream>>>(probs, out + (size_t)BATCH * SEQ * ODIM);
}